// Round 1
// baseline (2148.162 us; speedup 1.0000x reference)
//
#include <hip/hip_runtime.h>
#include <hip/hip_bf16.h>
#include <stdint.h>

typedef __bf16 bf16;
typedef bf16 bf16x8 __attribute__((ext_vector_type(8)));
typedef bf16 bf16x4 __attribute__((ext_vector_type(4)));
typedef float f32x4 __attribute__((ext_vector_type(4)));
typedef unsigned long long u64;

#define NB 8
#define NH 36
#define NW 100
#define YS 44
#define XSZ 108
#define PIX 28800

#define AS1 __attribute__((address_space(1)))
#define AS3 __attribute__((address_space(3)))

// async 16B global->LDS DMA. Dest = wave-uniform base + lane*16.
__device__ __forceinline__ void g2l16(const bf16* g, bf16* l) {
    __builtin_amdgcn_global_load_lds((const AS1 void*)g, (AS3 void*)l, 16, 0, 0);
}

// device-coherent (agent-scope, sc1) 8B load/store: hits the cross-XCD
// coherence point directly -> no buffer_wbl2 / buffer_inv needed around the
// msg-pass exchange. All hp accesses inside msg_fused go through these.
__device__ __forceinline__ u64 ld_agent(const bf16* p) {
    return __hip_atomic_load((u64*)p, __ATOMIC_RELAXED, __HIP_MEMORY_SCOPE_AGENT);
}
__device__ __forceinline__ void st_agent(bf16* p, u64 v) {
    __hip_atomic_store((u64*)p, v, __ATOMIC_RELAXED, __HIP_MEMORY_SCOPE_AGENT);
}

// ---------------- workspace layout ----------------
static constexpr size_t OFF_XP = 0;
static constexpr size_t SZ_XP  = (size_t)NB*YS*XSZ*512*2;
static constexpr size_t OFF_HP = OFF_XP + SZ_XP;
static constexpr size_t SZ_HP  = (size_t)NB*YS*XSZ*128*2;
static constexpr size_t OFF_A1 = OFF_HP + SZ_HP;
static constexpr size_t SZ_A1  = (size_t)1024*4608*2;
static constexpr size_t OFF_A2 = OFF_A1 + SZ_A1;
static constexpr size_t SZ_A2  = (size_t)128*1024*2;
static constexpr size_t OFF_AW = OFF_A2 + SZ_A2;
static constexpr size_t SZ_AW  = (size_t)4*9*128*128*2;
static constexpr size_t OFF_H1 = OFF_AW + SZ_AW;
static constexpr size_t SZ_H1  = (size_t)PIX*1024*2;
static constexpr size_t OFF_S1 = OFF_H1 + SZ_H1;
static constexpr size_t OFF_T1 = OFF_S1 + 4096;
static constexpr size_t OFF_S2 = OFF_T1 + 4096;
static constexpr size_t OFF_T2 = OFF_S2 + 512;
static constexpr size_t OFF_H5 = OFF_T2 + 512;
static constexpr size_t SZ_H5  = (size_t)NB*5*3600*4;
static constexpr size_t OFF_P  = OFF_H5 + SZ_H5;
static constexpr size_t OFF_F  = OFF_P + SZ_H5;
static constexpr size_t OFF_G  = OFF_F + 144128;
static constexpr size_t OFF_BAR = OFF_G + 4096;      // 8 x u32 barrier counters

// ---------------- prep kernels ----------------
__global__ __launch_bounds__(256) void zero_k(uint4* __restrict__ p, int n) {
    int i = blockIdx.x * 256 + threadIdx.x;
    if (i < n) p[i] = uint4{0u, 0u, 0u, 0u};
}

__global__ __launch_bounds__(256) void prep_x(const float* __restrict__ x, bf16* __restrict__ xp) {
    int bid = blockIdx.x;
    int xc = bid & 3;  int r = bid >> 2;
    int cc = r & 15;   r >>= 4;
    int yo = r % 36;   int b = r / 36;
    int ci0 = cc * 32, xo0 = xc * 32;
    int wdt = 100 - xo0; if (wdt > 32) wdt = 32;
    __shared__ bf16 T[32 * 33];
    int t = threadIdx.x;
    int cl = t >> 5, xl = t & 31;
    if (xl < wdt) {
#pragma unroll
        for (int i = 0; i < 4; i++) {
            int ci = ci0 + cl + 8 * i;
            T[(cl + 8 * i) * 33 + xl] = (bf16)x[((size_t)(b * 512 + ci) * 36 + yo) * 100 + xo0 + xl];
        }
    }
    __syncthreads();
    if (t < 128) {
        int xo2 = t >> 2, oct = t & 3;
        if (xo2 < wdt) {
            bf16x8 vv;
#pragma unroll
            for (int j = 0; j < 8; j++) vv[j] = T[(oct * 8 + j) * 33 + xo2];
            *(bf16x8*)(xp + ((size_t)((b * YS + yo + 4) * XSZ) + xo0 + xo2 + 4) * 512 + ci0 + oct * 8) = vv;
        }
    }
}

__global__ __launch_bounds__(256) void prep_w1a(const float* __restrict__ w, bf16* __restrict__ A) {
    int co = blockIdx.x;
    __shared__ bf16 Wl[4608];
    const float* src = w + (size_t)co * 4608;
    for (int v = threadIdx.x; v < 4608; v += 256) Wl[v] = (bf16)src[v];
    __syncthreads();
    bf16* dst = A + (size_t)co * 4608;
    for (int v = threadIdx.x; v < 4608; v += 256) {
        int rr = v >> 9, ci = v & 511;
        dst[v] = Wl[ci * 9 + rr];
    }
}

__global__ __launch_bounds__(256) void prep_w1b(const float* __restrict__ w, bf16* __restrict__ A) {
    int i = blockIdx.x * 256 + threadIdx.x;
    if (i < 131072) A[i] = (bf16)w[i];
}

__global__ __launch_bounds__(256) void prep_msg(const float* __restrict__ w0, const float* __restrict__ w1,
                                                const float* __restrict__ w2m, const float* __restrict__ w3,
                                                bf16* __restrict__ Aw) {
    int idx = blockIdx.x * 256 + threadIdx.x;
    if (idx >= 4 * 147456) return;
    int w = idx / 147456, r = idx % 147456;
    int t9 = r / 16384, r2 = r % 16384;
    int co = r2 >> 7, ci = r2 & 127;
    const float* s = (w == 0) ? w0 : (w == 1) ? w1 : (w == 2) ? w2m : w3;
    Aw[idx] = (bf16)s[(co * 128 + ci) * 9 + t9];
}

__global__ __launch_bounds__(256) void prep_bn(const float* g1, const float* b1, const float* m1, const float* v1,
                                               const float* g2, const float* b2i, const float* m2, const float* v2,
                                               float* s1, float* t1, float* s2, float* t2,
                                               unsigned* bar) {
    int i = blockIdx.x * 256 + threadIdx.x;
    if (i < 1024) {
        float s = g1[i] / sqrtf(v1[i] + 1e-5f);
        s1[i] = s; t1[i] = b1[i] - m1[i] * s;
    } else if (i < 1152) {
        int c = i - 1024;
        float s = g2[c] / sqrtf(v2[c] + 1e-5f);
        s2[c] = s; t2[c] = b2i[c] - m2[c] * s;
    } else if (i < 1160) {
        bar[i - 1152] = 0u;                 // reset msg barrier counters each launch
    }
}

// ---------------- conv1: implicit-im2col GEMM, global_load_lds + swizzled LDS ----------------
__device__ __forceinline__ void c1_koff(int ch, int& k0, int& xoff) {
    int ky = ch / 48, rem = ch - ky * 48;
    int kx = rem >> 4, c0 = (rem & 15) << 5;
    k0 = (ky * 3 + kx) * 512 + c0;
    xoff = (ky * XSZ + kx) * 2048 + c0;
}

__device__ __forceinline__ bf16x8 lds_frag(const bf16* S, int row, int q) {
    return *(const bf16x8*)(S + row * 32 + (((q ^ (row >> 1)) & 3) * 8));
}

__global__ __launch_bounds__(256) void conv1_gemm(const bf16* __restrict__ A, const bf16* __restrict__ xp,
                                                  const float* __restrict__ s1, const float* __restrict__ t1,
                                                  bf16* __restrict__ h1) {
    __shared__ __align__(16) bf16 SH[17408];
    bf16* As = SH;
    bf16* Bs = SH + 4096;
    const int t = threadIdx.x;
    const int pt = blockIdx.x, ct = blockIdx.y;
    const int co0 = ct * 128, p0 = pt * 128;
    const int wid = t >> 6, lane = t & 63;

    int aOff[2], bOff[2], ldsOff[2];
#pragma unroll
    for (int j = 0; j < 2; j++) {
        int p = wid * 128 + j * 64 + lane;
        int row = p >> 2;
        int oc = (p & 3) ^ ((p >> 3) & 3);
        aOff[j] = (co0 + row) * 4608 + oc * 8;
        int px = p0 + row;
        int b = px / 3600, rr = px % 3600;
        int y = rr / 100, xx = rr % 100;
        bOff[j] = ((b * YS + y) * XSZ + xx) * 512 + oc * 8;
        ldsOff[j] = (wid * 128 + j * 64) * 8;
    }

    const int mbase = (wid & 1) * 64, nbase = (wid >> 1) * 64;
    const int l15 = lane & 15, q = lane >> 4;

    f32x4 acc[4][4];
#pragma unroll
    for (int i = 0; i < 4; i++)
#pragma unroll
        for (int j = 0; j < 4; j++) acc[i][j] = f32x4{0.f, 0.f, 0.f, 0.f};

    for (int ch = 0; ch < 144; ch++) {
        int k0, xoff;
        c1_koff(ch, k0, xoff);
        __syncthreads();
#pragma unroll
        for (int j = 0; j < 2; j++) {
            g2l16(A + aOff[j] + k0, As + ldsOff[j]);
            g2l16(xp + bOff[j] + xoff, Bs + ldsOff[j]);
        }
        __syncthreads();
        bf16x8 af[4], bfv[4];
#pragma unroll
        for (int mt = 0; mt < 4; mt++) af[mt] = lds_frag(As, mbase + mt * 16 + l15, q);
#pragma unroll
        for (int nt = 0; nt < 4; nt++) bfv[nt] = lds_frag(Bs, nbase + nt * 16 + l15, q);
#pragma unroll
        for (int mt = 0; mt < 4; mt++)
#pragma unroll
            for (int nt = 0; nt < 4; nt++)
                acc[mt][nt] = __builtin_amdgcn_mfma_f32_16x16x32_bf16(af[mt], bfv[nt], acc[mt][nt], 0, 0, 0);
    }

    __syncthreads();
#pragma unroll
    for (int mt = 0; mt < 4; mt++) {
        int co = co0 + mbase + mt * 16 + q * 4;
        f32x4 sc = *(const f32x4*)(s1 + co);
        f32x4 tc = *(const f32x4*)(t1 + co);
#pragma unroll
        for (int nt = 0; nt < 4; nt++) {
            int pxl = nbase + nt * 16 + l15;
            bf16x4 o;
#pragma unroll
            for (int r = 0; r < 4; r++) {
                float v = acc[mt][nt][r] * sc[r] + tc[r];
                o[r] = (bf16)(v > 0.f ? v : 0.f);
            }
            *(bf16x4*)(SH + pxl * 136 + mbase + mt * 16 + q * 4) = o;
        }
    }
    __syncthreads();
#pragma unroll
    for (int i = 0; i < 8; i++) {
        int v = t + 256 * i;
        int pxl = v >> 4, c16 = v & 15;
        *(uint4*)(h1 + (size_t)(p0 + pxl) * 1024 + co0 + c16 * 8) = *(const uint4*)(SH + pxl * 136 + c16 * 8);
    }
}

// ---------------- conv2: 1x1 1024->128 ----------------
__global__ __launch_bounds__(256) void conv2_gemm(const bf16* __restrict__ A2, const bf16* __restrict__ h1,
                                                  const float* __restrict__ s2, const float* __restrict__ t2,
                                                  bf16* __restrict__ hp) {
    __shared__ __align__(16) bf16 SH[17408];
    bf16* As = SH;
    bf16* Bs = SH + 4096;
    const int t = threadIdx.x;
    const int p0 = blockIdx.x * 128;
    const int wid = t >> 6, lane = t & 63;

    int aOff[2], bOff[2], ldsOff[2];
#pragma unroll
    for (int j = 0; j < 2; j++) {
        int p = wid * 128 + j * 64 + lane;
        int row = p >> 2;
        int oc = (p & 3) ^ ((p >> 3) & 3);
        aOff[j] = row * 1024 + oc * 8;
        bOff[j] = (p0 + row) * 1024 + oc * 8;
        ldsOff[j] = (wid * 128 + j * 64) * 8;
    }
    const int mbase = (wid & 1) * 64, nbase = (wid >> 1) * 64;
    const int l15 = lane & 15, q = lane >> 4;

    f32x4 acc[4][4];
#pragma unroll
    for (int i = 0; i < 4; i++)
#pragma unroll
        for (int j = 0; j < 4; j++) acc[i][j] = f32x4{0.f, 0.f, 0.f, 0.f};

    for (int ch = 0; ch < 32; ch++) {
        int k0 = ch * 32;
        __syncthreads();
#pragma unroll
        for (int j = 0; j < 2; j++) {
            g2l16(A2 + aOff[j] + k0, As + ldsOff[j]);
            g2l16(h1 + bOff[j] + k0, Bs + ldsOff[j]);
        }
        __syncthreads();
        bf16x8 af[4], bfv[4];
#pragma unroll
        for (int mt = 0; mt < 4; mt++) af[mt] = lds_frag(As, mbase + mt * 16 + l15, q);
#pragma unroll
        for (int nt = 0; nt < 4; nt++) bfv[nt] = lds_frag(Bs, nbase + nt * 16 + l15, q);
#pragma unroll
        for (int mt = 0; mt < 4; mt++)
#pragma unroll
            for (int nt = 0; nt < 4; nt++)
                acc[mt][nt] = __builtin_amdgcn_mfma_f32_16x16x32_bf16(af[mt], bfv[nt], acc[mt][nt], 0, 0, 0);
    }

    __syncthreads();
#pragma unroll
    for (int mt = 0; mt < 4; mt++) {
        int co = mbase + mt * 16 + q * 4;
        f32x4 sc = *(const f32x4*)(s2 + co);
        f32x4 tc = *(const f32x4*)(t2 + co);
#pragma unroll
        for (int nt = 0; nt < 4; nt++) {
            int pxl = nbase + nt * 16 + l15;
            bf16x4 o;
#pragma unroll
            for (int r = 0; r < 4; r++) {
                float v = acc[mt][nt][r] * sc[r] + tc[r];
                o[r] = (bf16)(v > 0.f ? v : 0.f);
            }
            *(bf16x4*)(SH + pxl * 136 + co) = o;
        }
    }
    __syncthreads();
#pragma unroll
    for (int i = 0; i < 8; i++) {
        int v = t + 256 * i;
        int pxl = v >> 4, c16 = v & 15;
        int p = p0 + pxl;
        int b = p / 3600, rr = p % 3600;
        int y = rr / 100, xx = rr % 100;
        *(uint4*)(hp + (size_t)((b * YS + y + 4) * XSZ + xx + 4) * 128 + c16 * 8) = *(const uint4*)(SH + pxl * 136 + c16 * 8);
    }
}

// ---------------- fused message passes, 8 blocks per batch ----------------
// 64 blocks = 8 batches x 8 co-slices(16). Per wave: A slice = 36 frags =
// 144 VGPRs. Exchange redesign vs previous version:
//   * all hp traffic inside this kernel is agent-scope RELAXED atomics (sc1)
//     -> individually coherent at the cross-XCD point, so NO buffer_wbl2 /
//     buffer_inv storms on the critical path (the old per-poll-iteration
//     ACQUIRE invalidated the whole XCD L2 every spin).
//   * flag keeps release/acquire semantics, but poll is relaxed with one
//     acquire fence on exit (nothing msg-related is dirty in L2 -> cheap).
//   * the RMW 'cur' load is prefetched at step start (only this block ever
//     writes its own co-slice of row pos, so it is race-free any time in
//     the step) -> dependent L3-latency load moves off the barrier tail.
__device__ __forceinline__ bf16x8 awfrag2(const bf16* __restrict__ Aw, int ch, int cs, int l15, int q) {
    int t9 = ch >> 2, c0 = (ch & 3) << 5;
    return *(const bf16x8*)(Aw + (size_t)((t9 * 128 + cs * 16 + l15) << 7) + c0 + q * 8);
}

__device__ __forceinline__ void gbar(unsigned* ctr, int target) {
    // each wave's __syncthreads lowering drains its own vmcnt (sc1 stores
    // complete at the coherent point); explicit waitcnt is cheap insurance.
    asm volatile("s_waitcnt vmcnt(0)" ::: "memory");
    __syncthreads();
    if (threadIdx.x == 0) {
        __hip_atomic_fetch_add(ctr, 1u, __ATOMIC_RELEASE, __HIP_MEMORY_SCOPE_AGENT);
        while ((int)__hip_atomic_load(ctr, __ATOMIC_RELAXED, __HIP_MEMORY_SCOPE_AGENT) < target)
            __builtin_amdgcn_s_sleep(1);
        __builtin_amdgcn_fence(__ATOMIC_ACQUIRE, "agent");   // once, not per poll
    }
    __syncthreads();
}

template <int AX, int RV>
__device__ void msg_phase2(const bf16* __restrict__ Aw, bf16* __restrict__ hpb,
                           bf16* __restrict__ Rb, unsigned* ctr, int cs, int& ep) {
    constexpr int STEPS = (AX == 2) ? NH : NW;
    constexpr int NLIM  = (AX == 2) ? NW : NH;
    constexpr int NTW   = (AX == 2) ? 2 : 1;
    const int t = threadIdx.x, wid = t >> 6, lane = t & 63, l15 = lane & 15, q = lane >> 4;

    // this block's 16-co weight slice -> registers (same in all 4 waves)
    bf16x8 a[36];
#pragma unroll
    for (int ch = 0; ch < 36; ch++) a[ch] = awfrag2(Aw, ch, cs, l15, q);

    const int nb0 = (AX == 2) ? wid * 32 : wid * 16;
    bool act[NTW];
#pragma unroll
    for (int i = 0; i < NTW; i++) act[i] = (nb0 + i * 16) < NLIM;
    const int co = cs * 16 + q * 4;

    for (int s = 1; s < STEPS; s++) {
        int pos = RV ? (STEPS - 1 - s) : s;
        int prv = RV ? pos + 1 : pos - 1;

        // prefetch own-co 'cur' values for the RMW (race-free: only self
        // writes this co-slice of row pos, and only at the end of this step)
        size_t gaddr[NTW];
        u64 curv[NTW];
        bool ok[NTW];
#pragma unroll
        for (int i = 0; i < NTW; i++) {
            int n = nb0 + i * 16 + l15;
            ok[i] = act[i] && (n < NLIM);
            gaddr[i] = ok[i] ? ((AX == 2) ? ((size_t)(pos + 4) * XSZ + (n + 4)) * 128 + co
                                          : ((size_t)(n + 4) * XSZ + (pos + 4)) * 128 + co)
                             : (size_t)co;
            curv[i] = ld_agent(hpb + gaddr[i]);
        }

        // stage prev line (all 128 ci) into Rb via device-coherent loads
        if (AX == 2) {
            const bf16* src = hpb + (size_t)(prv + 4) * XSZ * 128;
            for (int v = t; v < 108 * 16; v += 256) {
                int px = v >> 4, c = (v & 15) * 8;
                u64 lo = ld_agent(src + px * 128 + c);
                u64 hi = ld_agent(src + px * 128 + c + 4);
                u64* d = (u64*)(Rb + px * 136 + c);
                d[0] = lo; d[1] = hi;
            }
        } else {
            const bf16* src = hpb + (size_t)(prv + 4) * 128;
            for (int v = t; v < 44 * 16; v += 256) {
                int ys = v >> 4, c = (v & 15) * 8;
                u64 lo = ld_agent(src + (size_t)ys * XSZ * 128 + c);
                u64 hi = ld_agent(src + (size_t)ys * XSZ * 128 + c + 4);
                u64* d = (u64*)(Rb + ys * 136 + c);
                d[0] = lo; d[1] = hi;
            }
        }
        __syncthreads();

        f32x4 acc[NTW];
#pragma unroll
        for (int i = 0; i < NTW; i++) acc[i] = f32x4{0.f, 0.f, 0.f, 0.f};
#pragma unroll
        for (int ch = 0; ch < 36; ch++) {
            int t9 = ch >> 2, c0 = (ch & 3) << 5;
#pragma unroll
            for (int i = 0; i < NTW; i++) {
                if (act[i]) {
                    bf16x8 bfv = *(const bf16x8*)(Rb + (nb0 + i * 16 + l15 + t9) * 136 + c0 + q * 8);
                    acc[i] = __builtin_amdgcn_mfma_f32_16x16x32_bf16(a[ch], bfv, acc[i], 0, 0, 0);
                }
            }
        }

        // RMW this block's 16-co slice of row/col pos (cur already in regs)
#pragma unroll
        for (int i = 0; i < NTW; i++) {
            if (ok[i]) {
                bf16x4 cur = *(bf16x4*)&curv[i];
                bf16x4 o;
#pragma unroll
                for (int r = 0; r < 4; r++) {
                    float v = acc[i][r];
                    v = v > 0.f ? v : 0.f;
                    o[r] = (bf16)((float)cur[r] + v);
                }
                st_agent(hpb + gaddr[i], *(u64*)&o);
            }
        }
        ep++;
        gbar(ctr, 8 * ep);               // line complete + visible to group
    }
}

__global__ __launch_bounds__(256, 1) void msg_fused(const bf16* __restrict__ Aw, bf16* __restrict__ hp,
                                                    unsigned* __restrict__ bar) {
    __shared__ __align__(16) bf16 Rb[120 * 136];   // 32.6 KB (AX2 reads up to row 119)
    const int batch = blockIdx.x & 7;              // same XCD per batch-group (b%8)
    const int cs = blockIdx.x >> 3;                // co-slice 0..7
    bf16* hpb = hp + (size_t)batch * YS * XSZ * 128;
    unsigned* ctr = bar + batch;
    int ep = 0;
    msg_phase2<2, 0>(Aw + 0 * 147456, hpb, Rb, ctr, cs, ep);
    msg_phase2<2, 1>(Aw + 1 * 147456, hpb, Rb, ctr, cs, ep);
    msg_phase2<3, 0>(Aw + 2 * 147456, hpb, Rb, ctr, cs, ep);
    msg_phase2<3, 1>(Aw + 3 * 147456, hpb, Rb, ctr, cs, ep);
}

// ---------------- conv3 (1x1 128->5) + bias + softmax ----------------
__global__ __launch_bounds__(256) void conv3_softmax(const bf16* __restrict__ hp, const float* __restrict__ w2,
                                                     const float* __restrict__ b2, float* __restrict__ h5,
                                                     float* __restrict__ Pp) {
    int idx = blockIdx.x * 256 + threadIdx.x;
    if (idx >= PIX) return;
    int b = idx / 3600, rr = idx % 3600;
    int y = rr / 100, xx = rr % 100;
    const bf16* src = hp + ((size_t)(b * YS + y + 4) * XSZ + xx + 4) * 128;
    float a[5] = {b2[0], b2[1], b2[2], b2[3], b2[4]};
    for (int c8 = 0; c8 < 128; c8 += 8) {
        bf16x8 hv = *(const bf16x8*)(src + c8);
#pragma unroll
        for (int j = 0; j < 8; j++) {
            float hf = (float)hv[j];
            int c = c8 + j;
#pragma unroll
            for (int o = 0; o < 5; o++) a[o] += hf * w2[o * 128 + c];
        }
    }
    float mx = a[0];
#pragma unroll
    for (int o = 1; o < 5; o++) mx = a[o] > mx ? a[o] : mx;
    float e[5], sum = 0.f;
#pragma unroll
    for (int o = 0; o < 5; o++) { e[o] = expf(a[o] - mx); sum += e[o]; }
    float inv = 1.f / sum;
#pragma unroll
    for (int o = 0; o < 5; o++) {
        h5[(size_t)(b * 5 + o) * 3600 + rr] = a[o];
        Pp[(size_t)(b * 5 + o) * 3600 + rr] = e[o] * inv;
    }
}

__global__ __launch_bounds__(256) void pool_k(const float* __restrict__ Pp, float* __restrict__ F) {
    int idx = blockIdx.x * 256 + threadIdx.x;
    if (idx >= 36000) return;
    int xxp = idx % 50, r = idx / 50;
    int yyp = r % 18, bj = r / 18;
    int b = bj / 5, j = bj % 5;
    const float* Pb = Pp + (size_t)bj * 3600;
    float v = 0.25f * (Pb[(2 * yyp) * 100 + 2 * xxp] + Pb[(2 * yyp) * 100 + 2 * xxp + 1] +
                       Pb[(2 * yyp + 1) * 100 + 2 * xxp] + Pb[(2 * yyp + 1) * 100 + 2 * xxp + 1]);
    F[(size_t)b * 4500 + j * 900 + yyp * 50 + xxp] = v;
}

__global__ __launch_bounds__(64) void fc1_k(const float* __restrict__ F, const float* __restrict__ w,
                                            const float* __restrict__ bias, float* __restrict__ G) {
    int co = blockIdx.x;
    int lane = threadIdx.x;
    const float* wr = w + (size_t)co * 4500;
    float a[8] = {0.f, 0.f, 0.f, 0.f, 0.f, 0.f, 0.f, 0.f};
    for (int k = lane; k < 4500; k += 64) {
        float wv = wr[k];
#pragma unroll
        for (int b = 0; b < 8; b++) a[b] += wv * F[b * 4500 + k];
    }
#pragma unroll
    for (int b = 0; b < 8; b++) {
        float r = a[b];
        for (int off = 32; off; off >>= 1) r += __shfl_down(r, off);
        if (lane == 0) {
            float v = r + bias[co];
            G[b * 128 + co] = v > 0.f ? v : 0.f;
        }
    }
}

__global__ __launch_bounds__(64) void fc2_k(const float* __restrict__ G, const float* __restrict__ w,
                                            const float* __restrict__ bias, float* __restrict__ out) {
    int t = threadIdx.x;
    if (t >= 32) return;
    int b = t >> 2, j = t & 3;
    float a = bias[j];
    for (int c = 0; c < 128; c++) a += G[b * 128 + c] * w[j * 128 + c];
    out[9216000 + b * 4 + j] = 1.f / (1.f + expf(-a));
}

__global__ __launch_bounds__(256) void upsample_k(const float* __restrict__ h5, float* __restrict__ out) {
    int idx = blockIdx.x * 256 + threadIdx.x;
    if (idx >= 2304000) return;
    int xq = idx % 200, r = idx / 200;
    int yo = r % 288, bj = r / 288;
    const float* src = h5 + (size_t)bj * 3600;
    float py = yo * (35.0f / 287.0f);
    int i0 = (int)py; if (i0 > 34) i0 = 34;
    float fh = py - (float)i0;
    const float* r0 = src + i0 * 100;
    const float* r1 = r0 + 100;
    float4 o;
    float res[4];
#pragma unroll
    for (int e = 0; e < 4; e++) {
        int xo = xq * 4 + e;
        float px = xo * (99.0f / 799.0f);
        int j0 = (int)px; if (j0 > 98) j0 = 98;
        float fw = px - (float)j0;
        float aa = r0[j0] * (1.f - fh) + r1[j0] * fh;
        float bb = r0[j0 + 1] * (1.f - fh) + r1[j0 + 1] * fh;
        res[e] = aa * (1.f - fw) + bb * fw;
    }
    o.x = res[0]; o.y = res[1]; o.z = res[2]; o.w = res[3];
    *(float4*)(out + (size_t)idx * 4) = o;
}

// ---------------- launcher ----------------
extern "C" void kernel_launch(void* const* d_in, const int* in_sizes, int n_in,
                              void* d_out, int out_size, void* d_ws, size_t ws_size,
                              hipStream_t stream) {
    (void)in_sizes; (void)n_in; (void)out_size; (void)ws_size;
    const float* x    = (const float*)d_in[0];
    const float* w1a  = (const float*)d_in[1];
    const float* bn1g = (const float*)d_in[2];
    const float* bn1b = (const float*)d_in[3];
    const float* bn1m = (const float*)d_in[4];
    const float* bn1v = (const float*)d_in[5];
    const float* w1b  = (const float*)d_in[6];
    const float* bn2g = (const float*)d_in[7];
    const float* bn2b = (const float*)d_in[8];
    const float* bn2m = (const float*)d_in[9];
    const float* bn2v = (const float*)d_in[10];
    const float* wud  = (const float*)d_in[11];
    const float* wdu  = (const float*)d_in[12];
    const float* wlr  = (const float*)d_in[13];
    const float* wrl  = (const float*)d_in[14];
    const float* w2   = (const float*)d_in[15];
    const float* b2   = (const float*)d_in[16];
    const float* fc1w = (const float*)d_in[17];
    const float* fc1b = (const float*)d_in[18];
    const float* fc2w = (const float*)d_in[19];
    const float* fc2b = (const float*)d_in[20];
    float* out = (float*)d_out;
    char* ws = (char*)d_ws;
    bf16* xp = (bf16*)(ws + OFF_XP);
    bf16* hp = (bf16*)(ws + OFF_HP);
    bf16* A1 = (bf16*)(ws + OFF_A1);
    bf16* A2 = (bf16*)(ws + OFF_A2);
    bf16* Aw = (bf16*)(ws + OFF_AW);
    bf16* h1 = (bf16*)(ws + OFF_H1);
    float* s1 = (float*)(ws + OFF_S1);
    float* t1 = (float*)(ws + OFF_T1);
    float* s2 = (float*)(ws + OFF_S2);
    float* t2 = (float*)(ws + OFF_T2);
    float* h5 = (float*)(ws + OFF_H5);
    float* Pp = (float*)(ws + OFF_P);
    float* Ff = (float*)(ws + OFF_F);
    float* Gg = (float*)(ws + OFF_G);
    unsigned* bar = (unsigned*)(ws + OFF_BAR);

    int nzero = (int)((SZ_XP + SZ_HP) / 16);
    zero_k<<<(nzero + 255) / 256, 256, 0, stream>>>((uint4*)ws, nzero);
    prep_x<<<18432, 256, 0, stream>>>(x, xp);
    prep_w1a<<<1024, 256, 0, stream>>>(w1a, A1);
    prep_w1b<<<512, 256, 0, stream>>>(w1b, A2);
    prep_msg<<<2304, 256, 0, stream>>>(wud, wdu, wlr, wrl, Aw);
    prep_bn<<<5, 256, 0, stream>>>(bn1g, bn1b, bn1m, bn1v, bn2g, bn2b, bn2m, bn2v, s1, t1, s2, t2, bar);

    conv1_gemm<<<dim3(225, 8), 256, 0, stream>>>(A1, xp, s1, t1, h1);
    conv2_gemm<<<225, 256, 0, stream>>>(A2, h1, s2, t2, hp);

    msg_fused<<<64, 256, 0, stream>>>(Aw, hp, bar);

    conv3_softmax<<<113, 256, 0, stream>>>(hp, w2, b2, h5, Pp);
    pool_k<<<141, 256, 0, stream>>>(Pp, Ff);
    fc1_k<<<128, 64, 0, stream>>>(Ff, fc1w, fc1b, Gg);
    fc2_k<<<1, 64, 0, stream>>>(Gg, fc2w, fc2b, out);
    upsample_k<<<9000, 256, 0, stream>>>(h5, out);
}

// Round 2
// 1950.612 us; speedup vs baseline: 1.1013x; 1.1013x over previous
//
#include <hip/hip_runtime.h>
#include <hip/hip_bf16.h>
#include <stdint.h>

typedef __bf16 bf16;
typedef bf16 bf16x8 __attribute__((ext_vector_type(8)));
typedef bf16 bf16x4 __attribute__((ext_vector_type(4)));
typedef float f32x4 __attribute__((ext_vector_type(4)));
typedef unsigned long long u64;

#define NB 8
#define NH 36
#define NW 100
#define YS 44
#define XSZ 108
#define PIX 28800

#define AS1 __attribute__((address_space(1)))
#define AS3 __attribute__((address_space(3)))

// async 16B global->LDS DMA. Dest = wave-uniform base + lane*16.
__device__ __forceinline__ void g2l16(const bf16* g, bf16* l) {
    __builtin_amdgcn_global_load_lds((const AS1 void*)g, (AS3 void*)l, 16, 0, 0);
}

// ---------------- workspace layout ----------------
static constexpr size_t OFF_XP = 0;
static constexpr size_t SZ_XP  = (size_t)NB*YS*XSZ*512*2;
static constexpr size_t OFF_HP = OFF_XP + SZ_XP;
static constexpr size_t SZ_HP  = (size_t)NB*YS*XSZ*128*2;
static constexpr size_t OFF_A1 = OFF_HP + SZ_HP;
static constexpr size_t SZ_A1  = (size_t)1024*4608*2;
static constexpr size_t OFF_A2 = OFF_A1 + SZ_A1;
static constexpr size_t SZ_A2  = (size_t)128*1024*2;
static constexpr size_t OFF_AW = OFF_A2 + SZ_A2;
static constexpr size_t SZ_AW  = (size_t)4*9*128*128*2;
static constexpr size_t OFF_H1 = OFF_AW + SZ_AW;
static constexpr size_t SZ_H1  = (size_t)PIX*1024*2;
static constexpr size_t OFF_S1 = OFF_H1 + SZ_H1;
static constexpr size_t OFF_T1 = OFF_S1 + 4096;
static constexpr size_t OFF_S2 = OFF_T1 + 4096;
static constexpr size_t OFF_T2 = OFF_S2 + 512;
static constexpr size_t OFF_H5 = OFF_T2 + 512;
static constexpr size_t SZ_H5  = (size_t)NB*5*3600*4;
static constexpr size_t OFF_P  = OFF_H5 + SZ_H5;
static constexpr size_t OFF_F  = OFF_P + SZ_H5;
static constexpr size_t OFF_G  = OFF_F + 144128;
static constexpr size_t OFF_BAR = OFF_G + 4096;      // 8 x u32 (legacy, unused by msg now)

// ---------------- prep kernels ----------------
__global__ __launch_bounds__(256) void zero_k(uint4* __restrict__ p, int n) {
    int i = blockIdx.x * 256 + threadIdx.x;
    if (i < n) p[i] = uint4{0u, 0u, 0u, 0u};
}

__global__ __launch_bounds__(256) void prep_x(const float* __restrict__ x, bf16* __restrict__ xp) {
    int bid = blockIdx.x;
    int xc = bid & 3;  int r = bid >> 2;
    int cc = r & 15;   r >>= 4;
    int yo = r % 36;   int b = r / 36;
    int ci0 = cc * 32, xo0 = xc * 32;
    int wdt = 100 - xo0; if (wdt > 32) wdt = 32;
    __shared__ bf16 T[32 * 33];
    int t = threadIdx.x;
    int cl = t >> 5, xl = t & 31;
    if (xl < wdt) {
#pragma unroll
        for (int i = 0; i < 4; i++) {
            int ci = ci0 + cl + 8 * i;
            T[(cl + 8 * i) * 33 + xl] = (bf16)x[((size_t)(b * 512 + ci) * 36 + yo) * 100 + xo0 + xl];
        }
    }
    __syncthreads();
    if (t < 128) {
        int xo2 = t >> 2, oct = t & 3;
        if (xo2 < wdt) {
            bf16x8 vv;
#pragma unroll
            for (int j = 0; j < 8; j++) vv[j] = T[(oct * 8 + j) * 33 + xo2];
            *(bf16x8*)(xp + ((size_t)((b * YS + yo + 4) * XSZ) + xo0 + xo2 + 4) * 512 + ci0 + oct * 8) = vv;
        }
    }
}

__global__ __launch_bounds__(256) void prep_w1a(const float* __restrict__ w, bf16* __restrict__ A) {
    int co = blockIdx.x;
    __shared__ bf16 Wl[4608];
    const float* src = w + (size_t)co * 4608;
    for (int v = threadIdx.x; v < 4608; v += 256) Wl[v] = (bf16)src[v];
    __syncthreads();
    bf16* dst = A + (size_t)co * 4608;
    for (int v = threadIdx.x; v < 4608; v += 256) {
        int rr = v >> 9, ci = v & 511;
        dst[v] = Wl[ci * 9 + rr];
    }
}

__global__ __launch_bounds__(256) void prep_w1b(const float* __restrict__ w, bf16* __restrict__ A) {
    int i = blockIdx.x * 256 + threadIdx.x;
    if (i < 131072) A[i] = (bf16)w[i];
}

__global__ __launch_bounds__(256) void prep_msg(const float* __restrict__ w0, const float* __restrict__ w1,
                                                const float* __restrict__ w2m, const float* __restrict__ w3,
                                                bf16* __restrict__ Aw) {
    int idx = blockIdx.x * 256 + threadIdx.x;
    if (idx >= 4 * 147456) return;
    int w = idx / 147456, r = idx % 147456;
    int t9 = r / 16384, r2 = r % 16384;
    int co = r2 >> 7, ci = r2 & 127;
    const float* s = (w == 0) ? w0 : (w == 1) ? w1 : (w == 2) ? w2m : w3;
    Aw[idx] = (bf16)s[(co * 128 + ci) * 9 + t9];
}

__global__ __launch_bounds__(256) void prep_bn(const float* g1, const float* b1, const float* m1, const float* v1,
                                               const float* g2, const float* b2i, const float* m2, const float* v2,
                                               float* s1, float* t1, float* s2, float* t2,
                                               unsigned* bar) {
    int i = blockIdx.x * 256 + threadIdx.x;
    if (i < 1024) {
        float s = g1[i] / sqrtf(v1[i] + 1e-5f);
        s1[i] = s; t1[i] = b1[i] - m1[i] * s;
    } else if (i < 1152) {
        int c = i - 1024;
        float s = g2[c] / sqrtf(v2[c] + 1e-5f);
        s2[c] = s; t2[c] = b2i[c] - m2[c] * s;
    } else if (i < 1160) {
        bar[i - 1152] = 0u;                 // legacy reset (msg no longer uses it)
    }
}

// ---------------- conv1: implicit-im2col GEMM, global_load_lds + swizzled LDS ----------------
__device__ __forceinline__ void c1_koff(int ch, int& k0, int& xoff) {
    int ky = ch / 48, rem = ch - ky * 48;
    int kx = rem >> 4, c0 = (rem & 15) << 5;
    k0 = (ky * 3 + kx) * 512 + c0;
    xoff = (ky * XSZ + kx) * 2048 + c0;
}

__device__ __forceinline__ bf16x8 lds_frag(const bf16* S, int row, int q) {
    return *(const bf16x8*)(S + row * 32 + (((q ^ (row >> 1)) & 3) * 8));
}

__global__ __launch_bounds__(256) void conv1_gemm(const bf16* __restrict__ A, const bf16* __restrict__ xp,
                                                  const float* __restrict__ s1, const float* __restrict__ t1,
                                                  bf16* __restrict__ h1) {
    __shared__ __align__(16) bf16 SH[17408];
    bf16* As = SH;
    bf16* Bs = SH + 4096;
    const int t = threadIdx.x;
    const int pt = blockIdx.x, ct = blockIdx.y;
    const int co0 = ct * 128, p0 = pt * 128;
    const int wid = t >> 6, lane = t & 63;

    int aOff[2], bOff[2], ldsOff[2];
#pragma unroll
    for (int j = 0; j < 2; j++) {
        int p = wid * 128 + j * 64 + lane;
        int row = p >> 2;
        int oc = (p & 3) ^ ((p >> 3) & 3);
        aOff[j] = (co0 + row) * 4608 + oc * 8;
        int px = p0 + row;
        int b = px / 3600, rr = px % 3600;
        int y = rr / 100, xx = rr % 100;
        bOff[j] = ((b * YS + y) * XSZ + xx) * 512 + oc * 8;
        ldsOff[j] = (wid * 128 + j * 64) * 8;
    }

    const int mbase = (wid & 1) * 64, nbase = (wid >> 1) * 64;
    const int l15 = lane & 15, q = lane >> 4;

    f32x4 acc[4][4];
#pragma unroll
    for (int i = 0; i < 4; i++)
#pragma unroll
        for (int j = 0; j < 4; j++) acc[i][j] = f32x4{0.f, 0.f, 0.f, 0.f};

    for (int ch = 0; ch < 144; ch++) {
        int k0, xoff;
        c1_koff(ch, k0, xoff);
        __syncthreads();
#pragma unroll
        for (int j = 0; j < 2; j++) {
            g2l16(A + aOff[j] + k0, As + ldsOff[j]);
            g2l16(xp + bOff[j] + xoff, Bs + ldsOff[j]);
        }
        __syncthreads();
        bf16x8 af[4], bfv[4];
#pragma unroll
        for (int mt = 0; mt < 4; mt++) af[mt] = lds_frag(As, mbase + mt * 16 + l15, q);
#pragma unroll
        for (int nt = 0; nt < 4; nt++) bfv[nt] = lds_frag(Bs, nbase + nt * 16 + l15, q);
#pragma unroll
        for (int mt = 0; mt < 4; mt++)
#pragma unroll
            for (int nt = 0; nt < 4; nt++)
                acc[mt][nt] = __builtin_amdgcn_mfma_f32_16x16x32_bf16(af[mt], bfv[nt], acc[mt][nt], 0, 0, 0);
    }

    __syncthreads();
#pragma unroll
    for (int mt = 0; mt < 4; mt++) {
        int co = co0 + mbase + mt * 16 + q * 4;
        f32x4 sc = *(const f32x4*)(s1 + co);
        f32x4 tc = *(const f32x4*)(t1 + co);
#pragma unroll
        for (int nt = 0; nt < 4; nt++) {
            int pxl = nbase + nt * 16 + l15;
            bf16x4 o;
#pragma unroll
            for (int r = 0; r < 4; r++) {
                float v = acc[mt][nt][r] * sc[r] + tc[r];
                o[r] = (bf16)(v > 0.f ? v : 0.f);
            }
            *(bf16x4*)(SH + pxl * 136 + mbase + mt * 16 + q * 4) = o;
        }
    }
    __syncthreads();
#pragma unroll
    for (int i = 0; i < 8; i++) {
        int v = t + 256 * i;
        int pxl = v >> 4, c16 = v & 15;
        *(uint4*)(h1 + (size_t)(p0 + pxl) * 1024 + co0 + c16 * 8) = *(const uint4*)(SH + pxl * 136 + c16 * 8);
    }
}

// ---------------- conv2: 1x1 1024->128 ----------------
__global__ __launch_bounds__(256) void conv2_gemm(const bf16* __restrict__ A2, const bf16* __restrict__ h1,
                                                  const float* __restrict__ s2, const float* __restrict__ t2,
                                                  bf16* __restrict__ hp) {
    __shared__ __align__(16) bf16 SH[17408];
    bf16* As = SH;
    bf16* Bs = SH + 4096;
    const int t = threadIdx.x;
    const int p0 = blockIdx.x * 128;
    const int wid = t >> 6, lane = t & 63;

    int aOff[2], bOff[2], ldsOff[2];
#pragma unroll
    for (int j = 0; j < 2; j++) {
        int p = wid * 128 + j * 64 + lane;
        int row = p >> 2;
        int oc = (p & 3) ^ ((p >> 3) & 3);
        aOff[j] = row * 1024 + oc * 8;
        bOff[j] = (p0 + row) * 1024 + oc * 8;
        ldsOff[j] = (wid * 128 + j * 64) * 8;
    }
    const int mbase = (wid & 1) * 64, nbase = (wid >> 1) * 64;
    const int l15 = lane & 15, q = lane >> 4;

    f32x4 acc[4][4];
#pragma unroll
    for (int i = 0; i < 4; i++)
#pragma unroll
        for (int j = 0; j < 4; j++) acc[i][j] = f32x4{0.f, 0.f, 0.f, 0.f};

    for (int ch = 0; ch < 32; ch++) {
        int k0 = ch * 32;
        __syncthreads();
#pragma unroll
        for (int j = 0; j < 2; j++) {
            g2l16(A2 + aOff[j] + k0, As + ldsOff[j]);
            g2l16(h1 + bOff[j] + k0, Bs + ldsOff[j]);
        }
        __syncthreads();
        bf16x8 af[4], bfv[4];
#pragma unroll
        for (int mt = 0; mt < 4; mt++) af[mt] = lds_frag(As, mbase + mt * 16 + l15, q);
#pragma unroll
        for (int nt = 0; nt < 4; nt++) bfv[nt] = lds_frag(Bs, nbase + nt * 16 + l15, q);
#pragma unroll
        for (int mt = 0; mt < 4; mt++)
#pragma unroll
            for (int nt = 0; nt < 4; nt++)
                acc[mt][nt] = __builtin_amdgcn_mfma_f32_16x16x32_bf16(af[mt], bfv[nt], acc[mt][nt], 0, 0, 0);
    }

    __syncthreads();
#pragma unroll
    for (int mt = 0; mt < 4; mt++) {
        int co = mbase + mt * 16 + q * 4;
        f32x4 sc = *(const f32x4*)(s2 + co);
        f32x4 tc = *(const f32x4*)(t2 + co);
#pragma unroll
        for (int nt = 0; nt < 4; nt++) {
            int pxl = nbase + nt * 16 + l15;
            bf16x4 o;
#pragma unroll
            for (int r = 0; r < 4; r++) {
                float v = acc[mt][nt][r] * sc[r] + tc[r];
                o[r] = (bf16)(v > 0.f ? v : 0.f);
            }
            *(bf16x4*)(SH + pxl * 136 + co) = o;
        }
    }
    __syncthreads();
#pragma unroll
    for (int i = 0; i < 8; i++) {
        int v = t + 256 * i;
        int pxl = v >> 4, c16 = v & 15;
        int p = p0 + pxl;
        int b = p / 3600, rr = p % 3600;
        int y = rr / 100, xx = rr % 100;
        *(uint4*)(hp + (size_t)((b * YS + y + 4) * XSZ + xx + 4) * 128 + c16 * 8) = *(const uint4*)(SH + pxl * 136 + c16 * 8);
    }
}

// ---------------- fused message passes: ONE block (512 thr, 8 waves) per batch ----------------
// All 128 co live in one block: wave w owns co-slice w*16 (36 A-frags = 144 VGPR).
// The recurrence line ping-pongs entirely in LDS; the only per-step sync is
// __syncthreads. Zero cross-CU traffic on the serial critical path. hp is
// block-private here -> plain cached loads/stores (same-CU L1 coherence).
// LDS line layout: [row 0..119][ci 0..127], stride 136 (pad rows stay zero).
__device__ __forceinline__ bf16x8 awfrag2(const bf16* __restrict__ Aw, int ch, int cs, int l15, int q) {
    int t9 = ch >> 2, c0 = (ch & 3) << 5;
    return *(const bf16x8*)(Aw + (size_t)((t9 * 128 + cs * 16 + l15) << 7) + c0 + q * 8);
}

template <int AX, int RV>
__device__ void phase1cu(const bf16* __restrict__ Aw, bf16* __restrict__ hpb,
                         bf16*& bp, bf16*& bn) {
    constexpr int STEPS = (AX == 2) ? NH : NW;
    constexpr int NLIM  = (AX == 2) ? NW : NH;
    constexpr int NT    = (AX == 2) ? 7 : 3;        // 16-wide n-tiles covering NLIM
    const int t = threadIdx.x, wid = t >> 6, lane = t & 63, l15 = lane & 15, q = lane >> 4;

    // wave's 16-co weight slice -> registers
    bf16x8 a[36];
#pragma unroll
    for (int ch = 0; ch < 36; ch++) a[ch] = awfrag2(Aw, ch, wid, l15, q);

    const int co = wid * 16 + q * 4;
    const int pos0 = RV ? (STEPS - 1) : 0;

    // phase-start staging of initial line into bp (prev phases' final barrier
    // already ordered all prior writes)
    if (AX == 2) {
        // rows 0..107 = padded x-line of row pos0 (pads in hp are zero).
        // rows 108..119 are never written by any phase -> remain zero.
        const bf16* src = hpb + (size_t)(pos0 + 4) * XSZ * 128;
        for (int v = t; v < XSZ * 16; v += 512) {
            int px = v >> 4, c = (v & 15) * 8;
            *(uint4*)(bp + px * 136 + c) = *(const uint4*)(src + px * 128 + c);
        }
    } else {
        // zero rows 40..55 of BOTH buffers (dirtied by AX2; y-pad + read slack),
        // stage y rows 0..39 (rows 0..3 zero pads never written by AX2).
        for (int v = t; v < 2 * 16 * 17; v += 512) {
            int bsel = v >= 272;
            int r2 = v - bsel * 272;
            bf16* dst = bsel ? bn : bp;
            *(uint4*)(dst + (40 + (r2 / 17)) * 136 + (r2 % 17) * 8) = uint4{0u, 0u, 0u, 0u};
        }
        const bf16* src = hpb + (size_t)(pos0 + 4) * 128;
        for (int v = t; v < 40 * 16; v += 512) {
            int ys = v >> 4, c = (v & 15) * 8;
            *(uint4*)(bp + ys * 136 + c) = *(const uint4*)(src + (size_t)ys * XSZ * 128 + c);
        }
    }
    __syncthreads();

    for (int s = 1; s < STEPS; s++) {
        const int pos = RV ? (STEPS - 1 - s) : s;

        // prefetch own-co 'cur' values (L2-hot; completes under the MFMAs)
        int goff[NT];
        u64 curv[NT];
#pragma unroll
        for (int i = 0; i < NT; i++) {
            int n = i * 16 + l15;
            goff[i] = (AX == 2) ? ((pos + 4) * XSZ + n + 4) * 128 + co
                                : ((n + 4) * XSZ + pos + 4) * 128 + co;
            curv[i] = 0;
            if (n < NLIM) curv[i] = *(const u64*)(hpb + goff[i]);
        }

        f32x4 acc[NT];
#pragma unroll
        for (int i = 0; i < NT; i++) acc[i] = f32x4{0.f, 0.f, 0.f, 0.f};
#pragma unroll
        for (int ch = 0; ch < 36; ch++) {
            const int t9 = ch >> 2, c0 = (ch & 3) << 5;
            const bf16* base = bp + (l15 + t9) * 136 + c0 + q * 8;
#pragma unroll
            for (int i = 0; i < NT; i++) {
                bf16x8 bfv = *(const bf16x8*)(base + i * 16 * 136);
                acc[i] = __builtin_amdgcn_mfma_f32_16x16x32_bf16(a[ch], bfv, acc[i], 0, 0, 0);
            }
        }

        // epilogue: new = cur + relu(acc); -> global hp AND next line buffer
#pragma unroll
        for (int i = 0; i < NT; i++) {
            int n = i * 16 + l15;
            if (n < NLIM) {
                bf16x4 cur = *(bf16x4*)&curv[i];
                bf16x4 o;
#pragma unroll
                for (int r = 0; r < 4; r++) {
                    float v = acc[i][r];
                    v = v > 0.f ? v : 0.f;
                    o[r] = (bf16)((float)cur[r] + v);
                }
                *(u64*)(hpb + goff[i]) = *(u64*)&o;
                *(u64*)(bn + (n + 4) * 136 + co) = *(u64*)&o;
            }
        }
        __syncthreads();
        bf16* tmp = bp; bp = bn; bn = tmp;
    }
}

__global__ __launch_bounds__(512, 2) void msg_fused(const bf16* __restrict__ Aw, bf16* __restrict__ hp) {
    __shared__ __align__(16) bf16 BUF[2][120 * 136];   // 2 x 32.6 KB ping-pong line buffers
    const int batch = blockIdx.x;
    bf16* hpb = hp + (size_t)batch * YS * XSZ * 128;
    // zero both buffers once (pad rows must start zero)
    for (int v = threadIdx.x; v < 2 * 120 * 17; v += 512)
        ((uint4*)BUF)[v] = uint4{0u, 0u, 0u, 0u};
    __syncthreads();
    bf16* bp = BUF[0];
    bf16* bn = BUF[1];
    phase1cu<2, 0>(Aw + 0 * 147456, hpb, bp, bn);
    phase1cu<2, 1>(Aw + 1 * 147456, hpb, bp, bn);
    phase1cu<3, 0>(Aw + 2 * 147456, hpb, bp, bn);
    phase1cu<3, 1>(Aw + 3 * 147456, hpb, bp, bn);
}

// ---------------- conv3 (1x1 128->5) + bias + softmax ----------------
__global__ __launch_bounds__(256) void conv3_softmax(const bf16* __restrict__ hp, const float* __restrict__ w2,
                                                     const float* __restrict__ b2, float* __restrict__ h5,
                                                     float* __restrict__ Pp) {
    int idx = blockIdx.x * 256 + threadIdx.x;
    if (idx >= PIX) return;
    int b = idx / 3600, rr = idx % 3600;
    int y = rr / 100, xx = rr % 100;
    const bf16* src = hp + ((size_t)(b * YS + y + 4) * XSZ + xx + 4) * 128;
    float a[5] = {b2[0], b2[1], b2[2], b2[3], b2[4]};
    for (int c8 = 0; c8 < 128; c8 += 8) {
        bf16x8 hv = *(const bf16x8*)(src + c8);
#pragma unroll
        for (int j = 0; j < 8; j++) {
            float hf = (float)hv[j];
            int c = c8 + j;
#pragma unroll
            for (int o = 0; o < 5; o++) a[o] += hf * w2[o * 128 + c];
        }
    }
    float mx = a[0];
#pragma unroll
    for (int o = 1; o < 5; o++) mx = a[o] > mx ? a[o] : mx;
    float e[5], sum = 0.f;
#pragma unroll
    for (int o = 0; o < 5; o++) { e[o] = expf(a[o] - mx); sum += e[o]; }
    float inv = 1.f / sum;
#pragma unroll
    for (int o = 0; o < 5; o++) {
        h5[(size_t)(b * 5 + o) * 3600 + rr] = a[o];
        Pp[(size_t)(b * 5 + o) * 3600 + rr] = e[o] * inv;
    }
}

__global__ __launch_bounds__(256) void pool_k(const float* __restrict__ Pp, float* __restrict__ F) {
    int idx = blockIdx.x * 256 + threadIdx.x;
    if (idx >= 36000) return;
    int xxp = idx % 50, r = idx / 50;
    int yyp = r % 18, bj = r / 18;
    int b = bj / 5, j = bj % 5;
    const float* Pb = Pp + (size_t)bj * 3600;
    float v = 0.25f * (Pb[(2 * yyp) * 100 + 2 * xxp] + Pb[(2 * yyp) * 100 + 2 * xxp + 1] +
                       Pb[(2 * yyp + 1) * 100 + 2 * xxp] + Pb[(2 * yyp + 1) * 100 + 2 * xxp + 1]);
    F[(size_t)b * 4500 + j * 900 + yyp * 50 + xxp] = v;
}

__global__ __launch_bounds__(64) void fc1_k(const float* __restrict__ F, const float* __restrict__ w,
                                            const float* __restrict__ bias, float* __restrict__ G) {
    int co = blockIdx.x;
    int lane = threadIdx.x;
    const float* wr = w + (size_t)co * 4500;
    float a[8] = {0.f, 0.f, 0.f, 0.f, 0.f, 0.f, 0.f, 0.f};
    for (int k = lane; k < 4500; k += 64) {
        float wv = wr[k];
#pragma unroll
        for (int b = 0; b < 8; b++) a[b] += wv * F[b * 4500 + k];
    }
#pragma unroll
    for (int b = 0; b < 8; b++) {
        float r = a[b];
        for (int off = 32; off; off >>= 1) r += __shfl_down(r, off);
        if (lane == 0) {
            float v = r + bias[co];
            G[b * 128 + co] = v > 0.f ? v : 0.f;
        }
    }
}

__global__ __launch_bounds__(64) void fc2_k(const float* __restrict__ G, const float* __restrict__ w,
                                            const float* __restrict__ bias, float* __restrict__ out) {
    int t = threadIdx.x;
    if (t >= 32) return;
    int b = t >> 2, j = t & 3;
    float a = bias[j];
    for (int c = 0; c < 128; c++) a += G[b * 128 + c] * w[j * 128 + c];
    out[9216000 + b * 4 + j] = 1.f / (1.f + expf(-a));
}

__global__ __launch_bounds__(256) void upsample_k(const float* __restrict__ h5, float* __restrict__ out) {
    int idx = blockIdx.x * 256 + threadIdx.x;
    if (idx >= 2304000) return;
    int xq = idx % 200, r = idx / 200;
    int yo = r % 288, bj = r / 288;
    const float* src = h5 + (size_t)bj * 3600;
    float py = yo * (35.0f / 287.0f);
    int i0 = (int)py; if (i0 > 34) i0 = 34;
    float fh = py - (float)i0;
    const float* r0 = src + i0 * 100;
    const float* r1 = r0 + 100;
    float4 o;
    float res[4];
#pragma unroll
    for (int e = 0; e < 4; e++) {
        int xo = xq * 4 + e;
        float px = xo * (99.0f / 799.0f);
        int j0 = (int)px; if (j0 > 98) j0 = 98;
        float fw = px - (float)j0;
        float aa = r0[j0] * (1.f - fh) + r1[j0] * fh;
        float bb = r0[j0 + 1] * (1.f - fh) + r1[j0 + 1] * fh;
        res[e] = aa * (1.f - fw) + bb * fw;
    }
    o.x = res[0]; o.y = res[1]; o.z = res[2]; o.w = res[3];
    *(float4*)(out + (size_t)idx * 4) = o;
}

// ---------------- launcher ----------------
extern "C" void kernel_launch(void* const* d_in, const int* in_sizes, int n_in,
                              void* d_out, int out_size, void* d_ws, size_t ws_size,
                              hipStream_t stream) {
    (void)in_sizes; (void)n_in; (void)out_size; (void)ws_size;
    const float* x    = (const float*)d_in[0];
    const float* w1a  = (const float*)d_in[1];
    const float* bn1g = (const float*)d_in[2];
    const float* bn1b = (const float*)d_in[3];
    const float* bn1m = (const float*)d_in[4];
    const float* bn1v = (const float*)d_in[5];
    const float* w1b  = (const float*)d_in[6];
    const float* bn2g = (const float*)d_in[7];
    const float* bn2b = (const float*)d_in[8];
    const float* bn2m = (const float*)d_in[9];
    const float* bn2v = (const float*)d_in[10];
    const float* wud  = (const float*)d_in[11];
    const float* wdu  = (const float*)d_in[12];
    const float* wlr  = (const float*)d_in[13];
    const float* wrl  = (const float*)d_in[14];
    const float* w2   = (const float*)d_in[15];
    const float* b2   = (const float*)d_in[16];
    const float* fc1w = (const float*)d_in[17];
    const float* fc1b = (const float*)d_in[18];
    const float* fc2w = (const float*)d_in[19];
    const float* fc2b = (const float*)d_in[20];
    float* out = (float*)d_out;
    char* ws = (char*)d_ws;
    bf16* xp = (bf16*)(ws + OFF_XP);
    bf16* hp = (bf16*)(ws + OFF_HP);
    bf16* A1 = (bf16*)(ws + OFF_A1);
    bf16* A2 = (bf16*)(ws + OFF_A2);
    bf16* Aw = (bf16*)(ws + OFF_AW);
    bf16* h1 = (bf16*)(ws + OFF_H1);
    float* s1 = (float*)(ws + OFF_S1);
    float* t1 = (float*)(ws + OFF_T1);
    float* s2 = (float*)(ws + OFF_S2);
    float* t2 = (float*)(ws + OFF_T2);
    float* h5 = (float*)(ws + OFF_H5);
    float* Pp = (float*)(ws + OFF_P);
    float* Ff = (float*)(ws + OFF_F);
    float* Gg = (float*)(ws + OFF_G);
    unsigned* bar = (unsigned*)(ws + OFF_BAR);

    int nzero = (int)((SZ_XP + SZ_HP) / 16);
    zero_k<<<(nzero + 255) / 256, 256, 0, stream>>>((uint4*)ws, nzero);
    prep_x<<<18432, 256, 0, stream>>>(x, xp);
    prep_w1a<<<1024, 256, 0, stream>>>(w1a, A1);
    prep_w1b<<<512, 256, 0, stream>>>(w1b, A2);
    prep_msg<<<2304, 256, 0, stream>>>(wud, wdu, wlr, wrl, Aw);
    prep_bn<<<5, 256, 0, stream>>>(bn1g, bn1b, bn1m, bn1v, bn2g, bn2b, bn2m, bn2v, s1, t1, s2, t2, bar);

    conv1_gemm<<<dim3(225, 8), 256, 0, stream>>>(A1, xp, s1, t1, h1);
    conv2_gemm<<<225, 256, 0, stream>>>(A2, h1, s2, t2, hp);

    msg_fused<<<8, 512, 0, stream>>>(Aw, hp);

    conv3_softmax<<<113, 256, 0, stream>>>(hp, w2, b2, h5, Pp);
    pool_k<<<141, 256, 0, stream>>>(Pp, Ff);
    fc1_k<<<128, 64, 0, stream>>>(Ff, fc1w, fc1b, Gg);
    fc2_k<<<1, 64, 0, stream>>>(Gg, fc2w, fc2b, out);
    upsample_k<<<9000, 256, 0, stream>>>(h5, out);
}